// Round 1
// 622.337 us; speedup vs baseline: 1.0273x; 1.0273x over previous
//
#include <hip/hip_runtime.h>
#include <stdint.h>

// MGMCGCN — 3x (binary-GCN + 5-step LSTM + fc/tanh).
// Dtypes: float inputs f32, adj int32, ALL OUTPUTS f32. Internal bf16 MFMA.
// N=4096, F=H=256, K=3, T=5, G=4H=1024.
// R1 change log: gemm_agg / lstm_mm / gemm_nt_ep converted from reg-staging to
// global_load_lds width-16 with LINEAR LDS (m93->m97 lever, +67% staging A/B);
// gemm_agg + lstm_mm get bijective XCD-chunked block swizzle (T1).
#define NN_ 4096
#define FD 256
#define HD 256
#define KC 3
#define GD 1024
#define SA 40    // padded LDS pitch (shorts): 80 B row stride (gemm_xw only)

typedef __attribute__((ext_vector_type(4))) unsigned int vu4;     // 16 B
typedef __attribute__((ext_vector_type(4))) int vi4;              // 16 B
typedef __attribute__((ext_vector_type(4))) float vf4;            // 16 B
typedef __attribute__((ext_vector_type(4))) unsigned short vus4;  // 8 B
typedef __attribute__((ext_vector_type(8))) short short8;         // bf16x8 MFMA frag
typedef __attribute__((ext_vector_type(4))) float f32x4;          // MFMA acc

typedef __attribute__((address_space(1))) const void GV;
typedef __attribute__((address_space(3))) void LV;
// async global->LDS DMA, 16 B/lane; LDS dest = wave-uniform base + lane*16.
__device__ __forceinline__ void gl16(const void* g, void* l) {
    __builtin_amdgcn_global_load_lds((GV*)g, (LV*)l, 16, 0, 0);
}

__device__ __forceinline__ float b2f(unsigned short u) {
    unsigned int v = ((unsigned int)u) << 16; float f; __builtin_memcpy(&f, &v, 4); return f;
}
__device__ __forceinline__ unsigned short f2b(float x) {
    unsigned int u; __builtin_memcpy(&u, &x, 4);
    u = (u + 0x7FFFu + ((u >> 16) & 1u)) >> 16;   // RNE
    return (unsigned short)u;
}
__device__ __forceinline__ void cvt8(const float* __restrict__ g, unsigned short* o) {
    vf4 a = *(const vf4*)g, b = *(const vf4*)(g + 4);
    o[0] = f2b(a[0]); o[1] = f2b(a[1]); o[2] = f2b(a[2]); o[3] = f2b(a[3]);
    o[4] = f2b(b[0]); o[5] = f2b(b[1]); o[6] = f2b(b[2]); o[7] = f2b(b[3]);
}
__device__ __forceinline__ float sigm(float v) { return 1.f / (1.f + __expf(-v)); }

// ---------------------------------------------------------------------------
// adj_pass: read adj int32 [N][N][K]; write (a) f32 0/1 interleaved copy to the
// d_out adj region, (b) bf16 deinterleaved planes abk[k][i][j]; compute dinv.
// ---------------------------------------------------------------------------
__global__ __launch_bounds__(256) void adj_pass(const int* __restrict__ adj,
        float* __restrict__ adj_out, unsigned short* __restrict__ abk,
        float* __restrict__ dinv) {
    const int i = blockIdx.x, t = threadIdx.x;
    const int* src = adj + (size_t)i * 12288;
    float* dstf = adj_out + (size_t)i * 12288;
    float s0 = 0.f, s1 = 0.f, s2 = 0.f;
#pragma unroll
    for (int it = 0; it < 4; ++it) {
        int jq = (it * 256 + t) * 4;
        vi4 a = *(const vi4*)(src + jq * 3);
        vi4 b = *(const vi4*)(src + jq * 3 + 4);
        vi4 c = *(const vi4*)(src + jq * 3 + 8);
        int vv[12] = {a[0],a[1],a[2],a[3],b[0],b[1],b[2],b[3],c[0],c[1],c[2],c[3]};
        float ff[12];
#pragma unroll
        for (int e = 0; e < 12; ++e) ff[e] = vv[e] ? 1.f : 0.f;
        vf4 w0 = {ff[0],ff[1],ff[2],ff[3]}, w1 = {ff[4],ff[5],ff[6],ff[7]}, w2 = {ff[8],ff[9],ff[10],ff[11]};
        *(vf4*)(dstf + jq * 3) = w0; *(vf4*)(dstf + jq * 3 + 4) = w1; *(vf4*)(dstf + jq * 3 + 8) = w2;
#pragma unroll
        for (int k = 0; k < 3; ++k) {
            vus4 w;
            w[0] = vv[k]     ? (unsigned short)0x3F80 : (unsigned short)0;
            w[1] = vv[3 + k] ? (unsigned short)0x3F80 : (unsigned short)0;
            w[2] = vv[6 + k] ? (unsigned short)0x3F80 : (unsigned short)0;
            w[3] = vv[9 + k] ? (unsigned short)0x3F80 : (unsigned short)0;
            *(vus4*)(abk + ((size_t)(k * NN_ + i)) * NN_ + jq) = w;
        }
        s0 += ff[0] + ff[3] + ff[6] + ff[9];
        s1 += ff[1] + ff[4] + ff[7] + ff[10];
        s2 += ff[2] + ff[5] + ff[8] + ff[11];
    }
    __shared__ float r0[256], r1[256], r2[256];
    r0[t] = s0; r1[t] = s1; r2[t] = s2;
    __syncthreads();
    for (int off = 128; off > 0; off >>= 1) {
        if (t < off) { r0[t] += r0[t + off]; r1[t] += r1[t + off]; r2[t] += r2[t + off]; }
        __syncthreads();
    }
    if (t == 0) {
        dinv[i]            = 1.f / sqrtf(1.f + r0[0]);
        dinv[NN_ + i]      = 1.f / sqrtf(1.f + r1[0]);
        dinv[2 * NN_ + i]  = 1.f / sqrtf(1.f + r2[0]);
    }
}

// ---------------------------------------------------------------------------
// wcvt: one-time f32->bf16 of [wih | whh | fcw] into contiguous wb.
// ---------------------------------------------------------------------------
__global__ __launch_bounds__(256) void wcvt(const float* __restrict__ wih,
        const float* __restrict__ whh, const float* __restrict__ fcw,
        unsigned short* __restrict__ wb) {
    size_t e = ((size_t)blockIdx.x * 256 + threadIdx.x) * 8;
    const float* src; size_t off;
    if (e < 786432)       { src = wih; off = e; }
    else if (e < 1572864) { src = whh; off = e - 786432; }
    else                  { src = fcw; off = e - 1572864; }
    alignas(16) unsigned short o[8];
    cvt8(src + off, o);
    *(vu4*)(wb + e) = *(vu4*)o;
}

// ---------------------------------------------------------------------------
// GEMM1: yT[k][h][j] = dinv[k][j] * (x @ gnn_w[k])[j][h] (transposed store).
// (f32 inputs -> in-loop bf16 conversion; stays reg-staged.)
// ---------------------------------------------------------------------------
__global__ __launch_bounds__(256) void gemm_xw(const float* __restrict__ x,
        const float* __restrict__ gw, const float* __restrict__ dinv,
        unsigned short* __restrict__ yT) {
    __shared__ __align__(16) unsigned short sA[64 * SA], sB[64 * SA];
    const int bi = blockIdx.x, bj = blockIdx.y, k = blockIdx.z;
    const int t = threadIdx.x, lane = t & 63, wave = t >> 6;
    const int m = lane & 15, q = lane >> 4, ko = q * 8;
    const int h0 = bj * 64;
    f32x4 acc[4] = {};
    const float* A0 = x + (size_t)(bi * 64) * FD;
    const float* B0 = gw + (size_t)k * FD * HD;
    const int r = t >> 2, c8 = (t & 3) << 3;
    const int fB = t >> 3, c8B = (t & 7) << 3;
    for (int k0 = 0; k0 < FD; k0 += 32) {
        alignas(16) unsigned short tA[8], tB[8];
        cvt8(A0 + (size_t)r * FD + k0 + c8, tA);
        *(vu4*)(sA + r * SA + c8) = *(vu4*)tA;
        cvt8(B0 + (size_t)(k0 + fB) * HD + h0 + c8B, tB);
#pragma unroll
        for (int e = 0; e < 8; ++e) sB[(c8B + e) * SA + fB] = tB[e];
        __syncthreads();
        short8 af = *(const short8*)(sA + (wave * 16 + m) * SA + ko);
#pragma unroll
        for (int ct = 0; ct < 4; ++ct) {
            short8 bf = *(const short8*)(sB + (ct * 16 + m) * SA + ko);
            acc[ct] = __builtin_amdgcn_mfma_f32_16x16x32_bf16(af, bf, acc[ct], 0, 0, 0);
        }
        __syncthreads();
    }
    unsigned short* yTk = yT + (size_t)k * HD * NN_;
#pragma unroll
    for (int ct = 0; ct < 4; ++ct)
#pragma unroll
        for (int r2 = 0; r2 < 4; ++r2) {
            int col = h0 + ct * 16 + m;
            int row = bi * 64 + wave * 16 + q * 4 + r2;
            yTk[(size_t)col * NN_ + row] = f2b(acc[ct][r2] * dinv[(size_t)k * NN_ + row]);
        }
}

// ---------------------------------------------------------------------------
// gemm_agg v4: per-k 128x128 tiles, 2x2 waves, j-split s=4.
// pbuf[s][k][i][h] = sum_{j in s} abk_k[i][j]*yT_k[h][j] (+self).
// Staging via global_load_lds (16 B/lane, linear LDS [128][32]).
// 1D grid 768 with XCD-chunked swizzle: bh-siblings (shared A tile) colocate.
// ---------------------------------------------------------------------------
__global__ __launch_bounds__(256) void gemm_agg(const unsigned short* __restrict__ abk,
        const unsigned short* __restrict__ yT, unsigned short* __restrict__ pbuf) {
    __shared__ __align__(16) unsigned short sA[128 * 32], sB[128 * 32];
    const int d = blockIdx.x;                  // 0..767
    const int w = (d & 7) * 96 + (d >> 3);     // bijective XCD-chunked remap
    const int bh = w & 1, bi = (w >> 1) & 31, z = w >> 6;
    const int k = z >> 2, s = z & 3;
    const int t = threadIdx.x, lane = t & 63, wave = t >> 6;
    const int wi = wave & 1, wh = wave >> 1;
    const int m = lane & 15, q = lane >> 4, ko = q * 8;
    const int i0 = bi * 128, h0 = bh * 128, jbase = s * 1024;
    f32x4 acc[4][4] = {};
    const int lrow = lane >> 2, lcol = (lane & 3) << 3;   // 4 lanes/row, 16 B each
    // wave stages A rows wave*32+{0,16}+lrow and B rows likewise (2+2 instr)
    const unsigned short* Ag0 = abk + ((size_t)(k * NN_ + i0 + wave * 32 + lrow)) * NN_ + jbase + lcol;
    const unsigned short* Ag1 = Ag0 + (size_t)16 * NN_;
    const unsigned short* Bg0 = yT + ((size_t)(k * 256 + h0 + wave * 32 + lrow)) * NN_ + jbase + lcol;
    const unsigned short* Bg1 = Bg0 + (size_t)16 * NN_;
    unsigned short* lA0 = sA + (wave * 32) * 32;
    unsigned short* lA1 = lA0 + 16 * 32;
    unsigned short* lB0 = sB + (wave * 32) * 32;
    unsigned short* lB1 = lB0 + 16 * 32;
    for (int j0 = 0; j0 < 1024; j0 += 32) {
        gl16(Ag0 + j0, lA0);
        gl16(Ag1 + j0, lA1);
        gl16(Bg0 + j0, lB0);
        gl16(Bg1 + j0, lB1);
        __syncthreads();
        short8 af[4], bf[4];
#pragma unroll
        for (int rt = 0; rt < 4; ++rt)
            af[rt] = *(const short8*)(sA + (wi * 64 + rt * 16 + m) * 32 + ko);
#pragma unroll
        for (int ct = 0; ct < 4; ++ct)
            bf[ct] = *(const short8*)(sB + (wh * 64 + ct * 16 + m) * 32 + ko);
#pragma unroll
        for (int ct = 0; ct < 4; ++ct)
#pragma unroll
            for (int rt = 0; rt < 4; ++rt)
                acc[rt][ct] = __builtin_amdgcn_mfma_f32_16x16x32_bf16(af[rt], bf[ct], acc[rt][ct], 0, 0, 0);
        __syncthreads();
    }
    const int addself = ((bi >> 3) == s);   // 128-row block lies in one 1024-chunk
#pragma unroll
    for (int rt = 0; rt < 4; ++rt)
#pragma unroll
        for (int ct = 0; ct < 4; ++ct)
#pragma unroll
            for (int r2 = 0; r2 < 4; ++r2) {
                int row = i0 + wi * 64 + rt * 16 + q * 4 + r2;
                int col = h0 + wh * 64 + ct * 16 + m;
                float v = acc[rt][ct][r2];
                if (addself) v += b2f(yT[((size_t)k * 256 + col) * NN_ + row]);
                pbuf[(((size_t)s * 3 + k) * NN_ + row) * 256 + col] = f2b(v);
            }
}

// ---------------------------------------------------------------------------
// agg_reduce: xt[k][i][h] = f2b(dinv[k][i] * (sum_s pbuf[s]) + gnnb[k][h])
// ---------------------------------------------------------------------------
__global__ __launch_bounds__(256) void agg_reduce(const unsigned short* __restrict__ pbuf,
        const float* __restrict__ dinv, const float* __restrict__ gnnb,
        unsigned short* __restrict__ xt) {
    size_t e8 = ((size_t)blockIdx.x * 256 + threadIdx.x) * 8;
    int k = (int)(e8 >> 20);
    int i = (int)((e8 >> 8) & 4095);
    int h = (int)(e8 & 255);
    float di = dinv[k * NN_ + i];
    const size_t KIH = (size_t)KC * NN_ * HD;
    alignas(16) unsigned short p0[8], p1[8], p2[8], p3[8], o[8];
    *(vu4*)p0 = *(const vu4*)(pbuf + 0 * KIH + e8);
    *(vu4*)p1 = *(const vu4*)(pbuf + 1 * KIH + e8);
    *(vu4*)p2 = *(const vu4*)(pbuf + 2 * KIH + e8);
    *(vu4*)p3 = *(const vu4*)(pbuf + 3 * KIH + e8);
#pragma unroll
    for (int e = 0; e < 8; ++e) {
        float v = b2f(p0[e]) + b2f(p1[e]) + b2f(p2[e]) + b2f(p3[e]);
        o[e] = f2b(di * v + gnnb[k * HD + h + e]);
    }
    *(vu4*)(xt + e8) = *(vu4*)o;
}

// ---------------------------------------------------------------------------
// lstm_mm v2: NT GEMM, all 4 gates per lane. Block = 128 rows x (32 ch x 4 g);
// staging via global_load_lds into linear LDS; sB rows = gate*32+ch (gate=wave
// stages its own W rows). 1D grid 768 with XCD-chunked swizzle (A-tile reuse
// across chb=8). kk = bn>>5.
//   mode 0 (gateX): v += bih+bhh; store gX2[row][ch][4] (coalesced vus4).
//   mode 1 (step):  g = v + gX2; cell update with cbuf (f32); write c, h.
// ---------------------------------------------------------------------------
__global__ __launch_bounds__(256) void lstm_mm(const unsigned short* __restrict__ A,
        const unsigned short* __restrict__ W, const float* __restrict__ b1,
        const float* __restrict__ b2, unsigned short* __restrict__ gX2,
        float* __restrict__ cbuf, unsigned short* __restrict__ hbuf, int mode) {
    __shared__ __align__(16) unsigned short sA[128 * 32];   // 8 KB
    __shared__ __align__(16) unsigned short sB[128 * 32];   // 8 KB, rows g*32+ch
    const int d = blockIdx.x;                  // 0..767
    const int w = (d & 7) * 96 + (d >> 3);     // bijective XCD-chunked remap
    const int chb = w & 7, bn = w >> 3;
    const int t = threadIdx.x, lane = t & 63, wave = t >> 6;
    const int m = lane & 15, q = lane >> 4, ko = q * 8;
    const int kk = bn >> 5;
    f32x4 acc[2][2][4] = {};   // [rt][cc][gate]
    const int lrow = lane >> 2, lcol = (lane & 3) << 3;
    const unsigned short* A0 = A + (size_t)bn * 128 * 256;
    const unsigned short* W0 = W + (size_t)kk * GD * 256 + (size_t)chb * 32 * 256;
    // A rows wave*32+{0,16}+lrow; B (gate=wave) rows wave*256+{0,16}+lrow
    const unsigned short* Ag0 = A0 + (size_t)(wave * 32 + lrow) * 256 + lcol;
    const unsigned short* Ag1 = Ag0 + 16 * 256;
    const unsigned short* Bg0 = W0 + (size_t)(wave * 256 + lrow) * 256 + lcol;
    const unsigned short* Bg1 = Bg0 + 16 * 256;
    unsigned short* lA0 = sA + (wave * 32) * 32;
    unsigned short* lA1 = lA0 + 16 * 32;
    unsigned short* lB0 = sB + (wave * 32) * 32;
    unsigned short* lB1 = lB0 + 16 * 32;
    for (int k0 = 0; k0 < 256; k0 += 32) {
        gl16(Ag0 + k0, lA0);
        gl16(Ag1 + k0, lA1);
        gl16(Bg0 + k0, lB0);
        gl16(Bg1 + k0, lB1);
        __syncthreads();
        short8 af[2];
#pragma unroll
        for (int rt = 0; rt < 2; ++rt)
            af[rt] = *(const short8*)(sA + (wave * 32 + rt * 16 + m) * 32 + ko);
#pragma unroll
        for (int g = 0; g < 4; ++g)
#pragma unroll
            for (int cc = 0; cc < 2; ++cc) {
                short8 bf = *(const short8*)(sB + (g * 32 + cc * 16 + m) * 32 + ko);
#pragma unroll
                for (int rt = 0; rt < 2; ++rt)
                    acc[rt][cc][g] = __builtin_amdgcn_mfma_f32_16x16x32_bf16(af[rt], bf, acc[rt][cc][g], 0, 0, 0);
            }
        __syncthreads();
    }
#pragma unroll
    for (int rt = 0; rt < 2; ++rt)
#pragma unroll
        for (int cc = 0; cc < 2; ++cc)
#pragma unroll
            for (int r2 = 0; r2 < 4; ++r2) {
                int row = bn * 128 + wave * 32 + rt * 16 + q * 4 + r2;   // 0..12287
                int ch = chb * 32 + cc * 16 + m;                          // 0..255
                size_t goff = ((size_t)row * 256 + ch) * 4;
                if (mode == 0) {
                    vus4 o;
#pragma unroll
                    for (int g = 0; g < 4; ++g) {
                        float v = acc[rt][cc][g][r2]
                                + b1[kk * GD + g * 256 + ch] + b2[kk * GD + g * 256 + ch];
                        o[g] = f2b(v);
                    }
                    *(vus4*)(gX2 + goff) = o;
                } else {
                    vus4 gv = *(const vus4*)(gX2 + goff);
                    float iv = acc[rt][cc][0][r2] + b2f(gv[0]);
                    float fv = acc[rt][cc][1][r2] + b2f(gv[1]);
                    float gg = acc[rt][cc][2][r2] + b2f(gv[2]);
                    float ov = acc[rt][cc][3][r2] + b2f(gv[3]);
                    size_t coff = (size_t)row * 256 + ch;
                    float cn = sigm(fv) * cbuf[coff] + sigm(iv) * tanhf(gg);
                    cbuf[coff] = cn;
                    hbuf[coff] = f2b(sigm(ov) * tanhf(cn));
                }
            }
}

// ---------------------------------------------------------------------------
// lstm_cell0: t=0 (h0=0,c0=0): c = sig(i)*tanh(g); h = sig(o)*tanh(c).
// ---------------------------------------------------------------------------
__global__ __launch_bounds__(256) void lstm_cell0(const unsigned short* __restrict__ gX2,
        float* __restrict__ cbuf, unsigned short* __restrict__ hbuf) {
    size_t e8 = ((size_t)blockIdx.x * 256 + threadIdx.x) * 8;
    size_t gb = e8 * 4;
    alignas(16) unsigned short gx[32], h8[8];
    alignas(16) float cv[8];
#pragma unroll
    for (int v = 0; v < 4; ++v)
        *(vu4*)(gx + v * 8) = *(const vu4*)(gX2 + gb + v * 8);
#pragma unroll
    for (int e = 0; e < 8; ++e) {
        float iv = b2f(gx[e * 4 + 0]), gg = b2f(gx[e * 4 + 2]), ov = b2f(gx[e * 4 + 3]);
        float cn = sigm(iv) * tanhf(gg);
        cv[e] = cn;
        h8[e] = f2b(sigm(ov) * tanhf(cn));
    }
    *(vf4*)(cbuf + e8)     = *(vf4*)cv;
    *(vf4*)(cbuf + e8 + 4) = *(vf4*)(cv + 4);
    *(vu4*)(hbuf + e8) = *(vu4*)h8;
}

// ---------------------------------------------------------------------------
// NT GEMM (fc): out[k][n][col] = tanh(A . W^T + b1). 64x64 tiles.
// Staging via global_load_lds (wave stages 16 A rows + 16 B rows).
// ---------------------------------------------------------------------------
__global__ __launch_bounds__(256) void gemm_nt_ep(const unsigned short* __restrict__ A,
        const unsigned short* __restrict__ W, const float* __restrict__ b1,
        unsigned short* __restrict__ outp, int COLS, int do_tanh) {
    __shared__ __align__(16) unsigned short sA[64 * 32], sB[64 * 32];
    const int bg = blockIdx.x, bn = blockIdx.y, k = blockIdx.z;
    const int t = threadIdx.x, lane = t & 63, wave = t >> 6;
    const int m = lane & 15, q = lane >> 4, ko = q * 8;
    f32x4 acc[4] = {};
    const int lrow = lane >> 2, lcol = (lane & 3) << 3;
    const unsigned short* A0 = A + ((size_t)k * NN_ + bn * 64) * HD;
    const unsigned short* W0 = W + ((size_t)k * COLS + bg * 64) * HD;
    const unsigned short* Ag = A0 + (size_t)(wave * 16 + lrow) * HD + lcol;
    const unsigned short* Bg = W0 + (size_t)(wave * 16 + lrow) * HD + lcol;
    unsigned short* lA = sA + (wave * 16) * 32;
    unsigned short* lB = sB + (wave * 16) * 32;
    for (int k0 = 0; k0 < HD; k0 += 32) {
        gl16(Ag + k0, lA);
        gl16(Bg + k0, lB);
        __syncthreads();
        short8 af = *(const short8*)(sA + (wave * 16 + m) * 32 + ko);
#pragma unroll
        for (int ct = 0; ct < 4; ++ct) {
            short8 bf = *(const short8*)(sB + (ct * 16 + m) * 32 + ko);
            acc[ct] = __builtin_amdgcn_mfma_f32_16x16x32_bf16(af, bf, acc[ct], 0, 0, 0);
        }
        __syncthreads();
    }
#pragma unroll
    for (int ct = 0; ct < 4; ++ct)
#pragma unroll
        for (int r2 = 0; r2 < 4; ++r2) {
            int col = bg * 64 + ct * 16 + m;
            int row = bn * 64 + wave * 16 + q * 4 + r2;
            float v = acc[ct][r2];
            if (b1) v += b1[(size_t)k * COLS + col];
            if (do_tanh) v = tanhf(v);
            outp[((size_t)k * NN_ + row) * COLS + col] = f2b(v);
        }
}

// ---------------------------------------------------------------------------
// final_ep: pred = sig_slice(x + mean_k delta); res[n][f][k] = sig_slice(x + delta_k)
// ---------------------------------------------------------------------------
__global__ __launch_bounds__(256) void final_ep(const float* __restrict__ x,
        const unsigned short* __restrict__ delta, float* __restrict__ pred,
        float* __restrict__ res) {
    int idx = blockIdx.x * 256 + threadIdx.x;
    size_t base = (size_t)idx * 8;
    int f0 = (int)(base & 255);
    alignas(16) unsigned short d0[8], d1[8], d2[8];
    alignas(16) float pr[8], rs[24];
    vf4 xa = *(const vf4*)(x + base), xb = *(const vf4*)(x + base + 4);
    float xs[8] = { xa[0], xa[1], xa[2], xa[3], xb[0], xb[1], xb[2], xb[3] };
    *(vu4*)d0 = *(const vu4*)(delta + base);
    *(vu4*)d1 = *(const vu4*)(delta + (size_t)NN_ * FD + base);
    *(vu4*)d2 = *(const vu4*)(delta + 2 * (size_t)NN_ * FD + base);
#pragma unroll
    for (int e = 0; e < 8; ++e) {
        int f = f0 + e;
        bool sg = (f >= 10) && (f < 253);
        float xf = xs[e];
        float da = b2f(d0[e]), db = b2f(d1[e]), dc = b2f(d2[e]);
        float dm = (da + db + dc) * (1.f / 3.f);
        float p = xf + dm; if (sg) p = sigm(p);
        pr[e] = p;
        float z0 = xf + da; if (sg) z0 = sigm(z0);
        float z1 = xf + db; if (sg) z1 = sigm(z1);
        float z2 = xf + dc; if (sg) z2 = sigm(z2);
        rs[e * 3 + 0] = z0; rs[e * 3 + 1] = z1; rs[e * 3 + 2] = z2;
    }
    *(vf4*)(pred + base)     = *(vf4*)pr;
    *(vf4*)(pred + base + 4) = *(vf4*)(pr + 4);
    size_t rb = base * 3;
#pragma unroll
    for (int v = 0; v < 6; ++v)
        *(vf4*)(res + rb + v * 4) = *(vf4*)(rs + v * 4);
}

extern "C" void kernel_launch(void* const* d_in, const int* in_sizes, int n_in,
                              void* d_out, int out_size, void* d_ws, size_t ws_size,
                              hipStream_t stream) {
    const float* x    = (const float*)d_in[0];
    const float* gnnw = (const float*)d_in[1];
    const float* gnnb = (const float*)d_in[2];
    const float* wih  = (const float*)d_in[3];
    const float* whh  = (const float*)d_in[4];
    const float* bih  = (const float*)d_in[5];
    const float* bhh  = (const float*)d_in[6];
    const float* fcw  = (const float*)d_in[7];
    const float* fcb  = (const float*)d_in[8];
    const int*   adj  = (const int*)d_in[9];

    float* out = (float*)d_out;
    float* out_pred = out;
    float* out_res  = out + (size_t)NN_ * FD;
    float* out_adj  = out + (size_t)NN_ * FD * 4;

    // ws layout (~155 MB):
    char* ws = (char*)d_ws;
    float*          dinv  = (float*)ws;                          // 49,152
    unsigned short* R1    = (unsigned short*)(ws + 49152);       // 6,291,456 (yT -> h)
    unsigned short* R2    = (unsigned short*)(ws + 6340608);     // 6,291,456 (xt -> delta)
    unsigned short* wb    = (unsigned short*)(ws + 12632064);    // 3,538,944
    unsigned short* pbuf  = (unsigned short*)(ws + 16171008);    // 25,165,824
    unsigned short* gX2   = pbuf;                                // later lifetime
    unsigned short* abk   = (unsigned short*)(ws + 41336832);    // 100,663,296
    float*          cbuf  = (float*)(ws + 142000128);            // 12,582,912 -> 154,583,040
    const unsigned short* wihb = wb;
    const unsigned short* whhb = wb + 786432;
    const unsigned short* fcwb = wb + 1572864;
    (void)ws_size; (void)in_sizes; (void)n_in; (void)out_size;

    wcvt<<<dim3(864), 256, 0, stream>>>(wih, whh, fcw, wb);
    adj_pass<<<dim3(4096), 256, 0, stream>>>(adj, out_adj, abk, dinv);
    gemm_xw<<<dim3(64, 4, 3), 256, 0, stream>>>(x, gnnw, dinv, R1 /*yT*/);
    gemm_agg<<<dim3(768), 256, 0, stream>>>(abk, R1 /*yT*/, pbuf);
    agg_reduce<<<dim3(1536), 256, 0, stream>>>(pbuf, dinv, gnnb, R2 /*xt*/);
    // gateX: A=xt, W=wih, +biases -> gX2 (gate-interleaved)
    lstm_mm<<<dim3(768), 256, 0, stream>>>(R2 /*xt*/, wihb, bih, bhh, gX2, nullptr, nullptr, 0);
    lstm_cell0<<<dim3(1536), 256, 0, stream>>>(gX2, cbuf, R1 /*h*/);
    for (int tstep = 1; tstep < 5; ++tstep)
        lstm_mm<<<dim3(768), 256, 0, stream>>>(R1 /*h*/, whhb, nullptr, nullptr, gX2, cbuf, R1 /*h*/, 1);
    gemm_nt_ep<<<dim3(4, 64, 3), 256, 0, stream>>>(R1 /*h_last*/, fcwb, fcb, R2 /*delta*/, FD, 1);
    final_ep<<<dim3(512), 256, 0, stream>>>(x, R2 /*delta*/, out_pred, out_res);
}

// Round 2
// 586.775 us; speedup vs baseline: 1.0896x; 1.0606x over previous
//
#include <hip/hip_runtime.h>
#include <stdint.h>

// MGMCGCN — 3x (binary-GCN + 5-step LSTM + fc/tanh).
// Dtypes: float inputs f32, adj int32, ALL OUTPUTS f32. Internal bf16 MFMA.
// N=4096, F=H=256, K=3, T=5, G=4H=1024.
// R2 change log:
//  - adjacency BIT-PACKED (6 MB) instead of bf16 planes (100 MB); gemm_agg
//    expands bits->bf16 A-fragments in-register (A-side HBM traffic ~0).
//  - wcvt folded into adj_pass; lstm_cell0 fused into lstm_mm mode 0;
//    gemm_nt_ep+final_ep merged into fc_final (delta stays in registers).
//  - launches 13 -> 10.
#define NN_ 4096
#define FD 256
#define HD 256
#define KC 3
#define GD 1024
#define SA 40    // padded LDS pitch (shorts): 80 B row stride (gemm_xw only)
#define BPITCH 144  // bitsA LDS row pitch (bytes), 16-aligned, breaks bank aliasing

typedef __attribute__((ext_vector_type(4))) unsigned int vu4;     // 16 B
typedef __attribute__((ext_vector_type(4))) int vi4;              // 16 B
typedef __attribute__((ext_vector_type(4))) float vf4;            // 16 B
typedef __attribute__((ext_vector_type(4))) unsigned short vus4;  // 8 B
typedef __attribute__((ext_vector_type(8))) short short8;         // bf16x8 MFMA frag
typedef __attribute__((ext_vector_type(4))) float f32x4;          // MFMA acc

typedef __attribute__((address_space(1))) const void GV;
typedef __attribute__((address_space(3))) void LV;
// async global->LDS DMA, 16 B/lane; LDS dest = wave-uniform base + lane*16.
__device__ __forceinline__ void gl16(const void* g, void* l) {
    __builtin_amdgcn_global_load_lds((GV*)g, (LV*)l, 16, 0, 0);
}

__device__ __forceinline__ float b2f(unsigned short u) {
    unsigned int v = ((unsigned int)u) << 16; float f; __builtin_memcpy(&f, &v, 4); return f;
}
__device__ __forceinline__ unsigned short f2b(float x) {
    unsigned int u; __builtin_memcpy(&u, &x, 4);
    u = (u + 0x7FFFu + ((u >> 16) & 1u)) >> 16;   // RNE
    return (unsigned short)u;
}
__device__ __forceinline__ void cvt8(const float* __restrict__ g, unsigned short* o) {
    vf4 a = *(const vf4*)g, b = *(const vf4*)(g + 4);
    o[0] = f2b(a[0]); o[1] = f2b(a[1]); o[2] = f2b(a[2]); o[3] = f2b(a[3]);
    o[4] = f2b(b[0]); o[5] = f2b(b[1]); o[6] = f2b(b[2]); o[7] = f2b(b[3]);
}
__device__ __forceinline__ float sigm(float v) { return 1.f / (1.f + __expf(-v)); }

// ---------------------------------------------------------------------------
// adj_pass (+fused wcvt): read adj int32 [N][N][K]; write (a) f32 0/1 copy to
// d_out, (b) BIT-PACKED planes abits[k][i][512 B]; compute dinv. Blocks < 864
// additionally convert one 2048-float chunk of [wih|whh|fcw] to bf16 wb.
// ---------------------------------------------------------------------------
__global__ __launch_bounds__(256) void adj_pass(const int* __restrict__ adj,
        float* __restrict__ adj_out, unsigned char* __restrict__ abits,
        float* __restrict__ dinv,
        const float* __restrict__ wih, const float* __restrict__ whh,
        const float* __restrict__ fcw, unsigned short* __restrict__ wb) {
    const int i = blockIdx.x, t = threadIdx.x;
    if (i < 864) {   // fused one-time weight conversion
        size_t e = ((size_t)i * 256 + t) * 8;
        const float* src; size_t off;
        if (e < 786432)       { src = wih; off = e; }
        else if (e < 1572864) { src = whh; off = e - 786432; }
        else                  { src = fcw; off = e - 1572864; }
        alignas(16) unsigned short o[8];
        cvt8(src + off, o);
        *(vu4*)(wb + e) = *(vu4*)o;
    }
    __shared__ unsigned char nib[3][1024];
    __shared__ float r0[256], r1[256], r2[256];
    const int* src = adj + (size_t)i * 12288;
    float* dstf = adj_out + (size_t)i * 12288;
    float s0 = 0.f, s1 = 0.f, s2 = 0.f;
#pragma unroll
    for (int it = 0; it < 4; ++it) {
        int p = it * 256 + t;          // nibble position = j/4
        int jq = p * 4;
        vi4 a = *(const vi4*)(src + jq * 3);
        vi4 b = *(const vi4*)(src + jq * 3 + 4);
        vi4 c = *(const vi4*)(src + jq * 3 + 8);
        int vv[12] = {a[0],a[1],a[2],a[3],b[0],b[1],b[2],b[3],c[0],c[1],c[2],c[3]};
        float ff[12];
#pragma unroll
        for (int e = 0; e < 12; ++e) ff[e] = vv[e] ? 1.f : 0.f;
        vf4 w0 = {ff[0],ff[1],ff[2],ff[3]}, w1 = {ff[4],ff[5],ff[6],ff[7]}, w2 = {ff[8],ff[9],ff[10],ff[11]};
        *(vf4*)(dstf + jq * 3) = w0; *(vf4*)(dstf + jq * 3 + 4) = w1; *(vf4*)(dstf + jq * 3 + 8) = w2;
#pragma unroll
        for (int k = 0; k < 3; ++k) {
            unsigned int nb = (vv[k] ? 1u : 0u) | (vv[3 + k] ? 2u : 0u)
                            | (vv[6 + k] ? 4u : 0u) | (vv[9 + k] ? 8u : 0u);
            nib[k][p] = (unsigned char)nb;
        }
        s0 += ff[0] + ff[3] + ff[6] + ff[9];
        s1 += ff[1] + ff[4] + ff[7] + ff[10];
        s2 += ff[2] + ff[5] + ff[8] + ff[11];
    }
    r0[t] = s0; r1[t] = s1; r2[t] = s2;
    __syncthreads();
    // pack nibbles -> 2 bytes per thread per k (bit j of byte j>>3 at pos j&7)
#pragma unroll
    for (int k = 0; k < 3; ++k) {
        unsigned int b0 = (unsigned int)nib[k][t * 4 + 0] | ((unsigned int)nib[k][t * 4 + 1] << 4);
        unsigned int b1 = (unsigned int)nib[k][t * 4 + 2] | ((unsigned int)nib[k][t * 4 + 3] << 4);
        *(unsigned short*)(abits + ((size_t)k * NN_ + i) * 512 + t * 2) =
            (unsigned short)(b0 | (b1 << 8));
    }
    for (int off = 128; off > 0; off >>= 1) {
        if (t < off) { r0[t] += r0[t + off]; r1[t] += r1[t + off]; r2[t] += r2[t + off]; }
        __syncthreads();
    }
    if (t == 0) {
        dinv[i]            = 1.f / sqrtf(1.f + r0[0]);
        dinv[NN_ + i]      = 1.f / sqrtf(1.f + r1[0]);
        dinv[2 * NN_ + i]  = 1.f / sqrtf(1.f + r2[0]);
    }
}

// ---------------------------------------------------------------------------
// GEMM1: yT[k][h][j] = dinv[k][j] * (x @ gnn_w[k])[j][h] (transposed store).
// (f32 inputs -> in-loop bf16 conversion; stays reg-staged.)
// ---------------------------------------------------------------------------
__global__ __launch_bounds__(256) void gemm_xw(const float* __restrict__ x,
        const float* __restrict__ gw, const float* __restrict__ dinv,
        unsigned short* __restrict__ yT) {
    __shared__ __align__(16) unsigned short sA[64 * SA], sB[64 * SA];
    const int bi = blockIdx.x, bj = blockIdx.y, k = blockIdx.z;
    const int t = threadIdx.x, lane = t & 63, wave = t >> 6;
    const int m = lane & 15, q = lane >> 4, ko = q * 8;
    const int h0 = bj * 64;
    f32x4 acc[4] = {};
    const float* A0 = x + (size_t)(bi * 64) * FD;
    const float* B0 = gw + (size_t)k * FD * HD;
    const int r = t >> 2, c8 = (t & 3) << 3;
    const int fB = t >> 3, c8B = (t & 7) << 3;
    for (int k0 = 0; k0 < FD; k0 += 32) {
        alignas(16) unsigned short tA[8], tB[8];
        cvt8(A0 + (size_t)r * FD + k0 + c8, tA);
        *(vu4*)(sA + r * SA + c8) = *(vu4*)tA;
        cvt8(B0 + (size_t)(k0 + fB) * HD + h0 + c8B, tB);
#pragma unroll
        for (int e = 0; e < 8; ++e) sB[(c8B + e) * SA + fB] = tB[e];
        __syncthreads();
        short8 af = *(const short8*)(sA + (wave * 16 + m) * SA + ko);
#pragma unroll
        for (int ct = 0; ct < 4; ++ct) {
            short8 bf = *(const short8*)(sB + (ct * 16 + m) * SA + ko);
            acc[ct] = __builtin_amdgcn_mfma_f32_16x16x32_bf16(af, bf, acc[ct], 0, 0, 0);
        }
        __syncthreads();
    }
    unsigned short* yTk = yT + (size_t)k * HD * NN_;
#pragma unroll
    for (int ct = 0; ct < 4; ++ct)
#pragma unroll
        for (int r2 = 0; r2 < 4; ++r2) {
            int col = h0 + ct * 16 + m;
            int row = bi * 64 + wave * 16 + q * 4 + r2;
            yTk[(size_t)col * NN_ + row] = f2b(acc[ct][r2] * dinv[(size_t)k * NN_ + row]);
        }
}

// ---------------------------------------------------------------------------
// gemm_agg v5: per-k 128x128 tiles, 2x2 waves, j-split s=4.
// A from BIT-PLANE: whole 128x1024-bit tile staged once in LDS (18 KB),
// expanded to bf16 fragments in-register (8 selects / fragment).
// B via global_load_lds. pbuf[s][k][i][h] = sum_{j in s} a*yT (+self).
// ---------------------------------------------------------------------------
__global__ __launch_bounds__(256) void gemm_agg(const unsigned char* __restrict__ abits,
        const unsigned short* __restrict__ yT, unsigned short* __restrict__ pbuf) {
    __shared__ __align__(16) unsigned char bitsA[128 * BPITCH];   // 18 KB
    __shared__ __align__(16) unsigned short sB[128 * 32];          // 8 KB
    const int d = blockIdx.x;                  // 0..767
    const int w = (d & 7) * 96 + (d >> 3);     // bijective XCD-chunked remap
    const int bh = w & 1, bi = (w >> 1) & 31, z = w >> 6;
    const int k = z >> 2, s = z & 3;
    const int t = threadIdx.x, lane = t & 63, wave = t >> 6;
    const int wi = wave & 1, wh = wave >> 1;
    const int m = lane & 15, q = lane >> 4, ko = q * 8;
    const int i0 = bi * 128, h0 = bh * 128, jbase = s * 1024;
    // stage the entire A bit-tile once: 128 rows x 128 B
    {
        const int row = t >> 1, half = t & 1;
        const unsigned char* bsrc = abits + ((size_t)k * NN_ + i0 + row) * 512 + s * 128 + half * 64;
        unsigned char* bdst = bitsA + row * BPITCH + half * 64;
        vu4 v0 = *(const vu4*)(bsrc);
        vu4 v1 = *(const vu4*)(bsrc + 16);
        vu4 v2 = *(const vu4*)(bsrc + 32);
        vu4 v3 = *(const vu4*)(bsrc + 48);
        *(vu4*)(bdst)      = v0;
        *(vu4*)(bdst + 16) = v1;
        *(vu4*)(bdst + 32) = v2;
        *(vu4*)(bdst + 48) = v3;
    }
    f32x4 acc[4][4] = {};
    const int lrow = lane >> 2, lcol = (lane & 3) << 3;   // 4 lanes/row, 16 B each
    const unsigned short* Bg0 = yT + ((size_t)(k * 256 + h0 + wave * 32 + lrow)) * NN_ + jbase + lcol;
    const unsigned short* Bg1 = Bg0 + (size_t)16 * NN_;
    unsigned short* lB0 = sB + (wave * 32) * 32;
    unsigned short* lB1 = lB0 + 16 * 32;
    const int arow = (wi * 64 + m) * BPITCH + q;   // byte base for this lane
    for (int j0 = 0; j0 < 1024; j0 += 32) {
        gl16(Bg0 + j0, lB0);
        gl16(Bg1 + j0, lB1);
        __syncthreads();
        const int jby = j0 >> 3;
        short8 af[4], bf[4];
#pragma unroll
        for (int rt = 0; rt < 4; ++rt) {
            unsigned int by = bitsA[arow + rt * 16 * BPITCH + jby];
#pragma unroll
            for (int e = 0; e < 8; ++e)
                af[rt][e] = (short)(((by >> e) & 1u) ? (short)0x3F80 : (short)0);
        }
#pragma unroll
        for (int ct = 0; ct < 4; ++ct)
            bf[ct] = *(const short8*)(sB + (wh * 64 + ct * 16 + m) * 32 + ko);
#pragma unroll
        for (int ct = 0; ct < 4; ++ct)
#pragma unroll
            for (int rt = 0; rt < 4; ++rt)
                acc[rt][ct] = __builtin_amdgcn_mfma_f32_16x16x32_bf16(af[rt], bf[ct], acc[rt][ct], 0, 0, 0);
        __syncthreads();
    }
    const int addself = ((bi >> 3) == s);   // 128-row block lies in one 1024-chunk
#pragma unroll
    for (int rt = 0; rt < 4; ++rt)
#pragma unroll
        for (int ct = 0; ct < 4; ++ct)
#pragma unroll
            for (int r2 = 0; r2 < 4; ++r2) {
                int row = i0 + wi * 64 + rt * 16 + q * 4 + r2;
                int col = h0 + wh * 64 + ct * 16 + m;
                float v = acc[rt][ct][r2];
                if (addself) v += b2f(yT[((size_t)k * 256 + col) * NN_ + row]);
                pbuf[(((size_t)s * 3 + k) * NN_ + row) * 256 + col] = f2b(v);
            }
}

// ---------------------------------------------------------------------------
// agg_reduce: xt[k][i][h] = f2b(dinv[k][i] * (sum_s pbuf[s]) + gnnb[k][h])
// ---------------------------------------------------------------------------
__global__ __launch_bounds__(256) void agg_reduce(const unsigned short* __restrict__ pbuf,
        const float* __restrict__ dinv, const float* __restrict__ gnnb,
        unsigned short* __restrict__ xt) {
    size_t e8 = ((size_t)blockIdx.x * 256 + threadIdx.x) * 8;
    int k = (int)(e8 >> 20);
    int i = (int)((e8 >> 8) & 4095);
    int h = (int)(e8 & 255);
    float di = dinv[k * NN_ + i];
    const size_t KIH = (size_t)KC * NN_ * HD;
    alignas(16) unsigned short p0[8], p1[8], p2[8], p3[8], o[8];
    *(vu4*)p0 = *(const vu4*)(pbuf + 0 * KIH + e8);
    *(vu4*)p1 = *(const vu4*)(pbuf + 1 * KIH + e8);
    *(vu4*)p2 = *(const vu4*)(pbuf + 2 * KIH + e8);
    *(vu4*)p3 = *(const vu4*)(pbuf + 3 * KIH + e8);
#pragma unroll
    for (int e = 0; e < 8; ++e) {
        float v = b2f(p0[e]) + b2f(p1[e]) + b2f(p2[e]) + b2f(p3[e]);
        o[e] = f2b(di * v + gnnb[k * HD + h + e]);
    }
    *(vu4*)(xt + e8) = *(vu4*)o;
}

// ---------------------------------------------------------------------------
// lstm_mm v3: NT GEMM, all 4 gates per lane; gl16 staging, linear LDS.
//   mode 0 (gateX): v += bih+bhh; store gX2; ALSO do the t=0 cell update
//                   (h0=c0=0): c = sig(i)*tanh(g), h = sig(o)*tanh(c).
//   mode 1 (step):  g = v + gX2; cell update with cbuf (f32); write c, h.
// ---------------------------------------------------------------------------
__global__ __launch_bounds__(256) void lstm_mm(const unsigned short* __restrict__ A,
        const unsigned short* __restrict__ W, const float* __restrict__ b1,
        const float* __restrict__ b2, unsigned short* __restrict__ gX2,
        float* __restrict__ cbuf, unsigned short* __restrict__ hbuf, int mode) {
    __shared__ __align__(16) unsigned short sA[128 * 32];   // 8 KB
    __shared__ __align__(16) unsigned short sB[128 * 32];   // 8 KB, rows g*32+ch
    const int d = blockIdx.x;                  // 0..767
    const int w = (d & 7) * 96 + (d >> 3);     // bijective XCD-chunked remap
    const int chb = w & 7, bn = w >> 3;
    const int t = threadIdx.x, lane = t & 63, wave = t >> 6;
    const int m = lane & 15, q = lane >> 4, ko = q * 8;
    const int kk = bn >> 5;
    f32x4 acc[2][2][4] = {};   // [rt][cc][gate]
    const int lrow = lane >> 2, lcol = (lane & 3) << 3;
    const unsigned short* A0 = A + (size_t)bn * 128 * 256;
    const unsigned short* W0 = W + (size_t)kk * GD * 256 + (size_t)chb * 32 * 256;
    const unsigned short* Ag0 = A0 + (size_t)(wave * 32 + lrow) * 256 + lcol;
    const unsigned short* Ag1 = Ag0 + 16 * 256;
    const unsigned short* Bg0 = W0 + (size_t)(wave * 256 + lrow) * 256 + lcol;
    const unsigned short* Bg1 = Bg0 + 16 * 256;
    unsigned short* lA0 = sA + (wave * 32) * 32;
    unsigned short* lA1 = lA0 + 16 * 32;
    unsigned short* lB0 = sB + (wave * 32) * 32;
    unsigned short* lB1 = lB0 + 16 * 32;
    for (int k0 = 0; k0 < 256; k0 += 32) {
        gl16(Ag0 + k0, lA0);
        gl16(Ag1 + k0, lA1);
        gl16(Bg0 + k0, lB0);
        gl16(Bg1 + k0, lB1);
        __syncthreads();
        short8 af[2];
#pragma unroll
        for (int rt = 0; rt < 2; ++rt)
            af[rt] = *(const short8*)(sA + (wave * 32 + rt * 16 + m) * 32 + ko);
#pragma unroll
        for (int g = 0; g < 4; ++g)
#pragma unroll
            for (int cc = 0; cc < 2; ++cc) {
                short8 bf = *(const short8*)(sB + (g * 32 + cc * 16 + m) * 32 + ko);
#pragma unroll
                for (int rt = 0; rt < 2; ++rt)
                    acc[rt][cc][g] = __builtin_amdgcn_mfma_f32_16x16x32_bf16(af[rt], bf, acc[rt][cc][g], 0, 0, 0);
            }
        __syncthreads();
    }
#pragma unroll
    for (int rt = 0; rt < 2; ++rt)
#pragma unroll
        for (int cc = 0; cc < 2; ++cc)
#pragma unroll
            for (int r2 = 0; r2 < 4; ++r2) {
                int row = bn * 128 + wave * 32 + rt * 16 + q * 4 + r2;   // 0..12287
                int ch = chb * 32 + cc * 16 + m;                          // 0..255
                size_t goff = ((size_t)row * 256 + ch) * 4;
                size_t coff = (size_t)row * 256 + ch;
                if (mode == 0) {
                    float v[4];
                    vus4 o;
#pragma unroll
                    for (int g = 0; g < 4; ++g) {
                        v[g] = acc[rt][cc][g][r2]
                             + b1[kk * GD + g * 256 + ch] + b2[kk * GD + g * 256 + ch];
                        o[g] = f2b(v[g]);
                    }
                    *(vus4*)(gX2 + goff) = o;
                    // fused t=0 cell (h0 = c0 = 0)
                    float cn = sigm(v[0]) * tanhf(v[2]);
                    cbuf[coff] = cn;
                    hbuf[coff] = f2b(sigm(v[3]) * tanhf(cn));
                } else {
                    vus4 gv = *(const vus4*)(gX2 + goff);
                    float iv = acc[rt][cc][0][r2] + b2f(gv[0]);
                    float fv = acc[rt][cc][1][r2] + b2f(gv[1]);
                    float gg = acc[rt][cc][2][r2] + b2f(gv[2]);
                    float ov = acc[rt][cc][3][r2] + b2f(gv[3]);
                    float cn = sigm(fv) * cbuf[coff] + sigm(iv) * tanhf(gg);
                    cbuf[coff] = cn;
                    hbuf[coff] = f2b(sigm(ov) * tanhf(cn));
                }
            }
}

// ---------------------------------------------------------------------------
// fc_final: one block computes 64x64 output for ALL 3 k (acc[3][4]), then the
// final epilogue inline: delta_k = tanh(h@fcw^T + fcb); pred/res from x+delta.
// delta never touches memory.
// ---------------------------------------------------------------------------
__global__ __launch_bounds__(256) void fc_final(const unsigned short* __restrict__ A,
        const unsigned short* __restrict__ W, const float* __restrict__ fcb,
        const float* __restrict__ x, float* __restrict__ pred, float* __restrict__ res) {
    __shared__ __align__(16) unsigned short sA[3][64 * 32], sB[3][64 * 32];  // 24 KB
    const int bg = blockIdx.x, bn = blockIdx.y;
    const int t = threadIdx.x, lane = t & 63, wave = t >> 6;
    const int m = lane & 15, q = lane >> 4, ko = q * 8;
    f32x4 acc[3][4] = {};
    const int lrow = lane >> 2, lcol = (lane & 3) << 3;
    const unsigned short* Ag[3]; const unsigned short* Bg[3];
#pragma unroll
    for (int k = 0; k < 3; ++k) {
        Ag[k] = A + ((size_t)k * NN_ + bn * 64 + wave * 16 + lrow) * HD + lcol;
        Bg[k] = W + ((size_t)k * FD + bg * 64 + wave * 16 + lrow) * HD + lcol;
    }
    for (int k0 = 0; k0 < HD; k0 += 32) {
#pragma unroll
        for (int k = 0; k < 3; ++k) {
            gl16(Ag[k] + k0, sA[k] + (wave * 16) * 32);
            gl16(Bg[k] + k0, sB[k] + (wave * 16) * 32);
        }
        __syncthreads();
#pragma unroll
        for (int k = 0; k < 3; ++k) {
            short8 af = *(const short8*)(sA[k] + (wave * 16 + m) * 32 + ko);
#pragma unroll
            for (int ct = 0; ct < 4; ++ct) {
                short8 bf = *(const short8*)(sB[k] + (ct * 16 + m) * 32 + ko);
                acc[k][ct] = __builtin_amdgcn_mfma_f32_16x16x32_bf16(af, bf, acc[k][ct], 0, 0, 0);
            }
        }
        __syncthreads();
    }
#pragma unroll
    for (int ct = 0; ct < 4; ++ct)
#pragma unroll
        for (int r2 = 0; r2 < 4; ++r2) {
            int col = bg * 64 + ct * 16 + m;
            int row = bn * 64 + wave * 16 + q * 4 + r2;
            float d0 = tanhf(acc[0][ct][r2] + fcb[col]);
            float d1 = tanhf(acc[1][ct][r2] + fcb[FD + col]);
            float d2 = tanhf(acc[2][ct][r2] + fcb[2 * FD + col]);
            float xf = x[(size_t)row * FD + col];
            bool sg = (col >= 10) && (col < 253);
            float dm = (d0 + d1 + d2) * (1.f / 3.f);
            float p = xf + dm; if (sg) p = sigm(p);
            pred[(size_t)row * FD + col] = p;
            float z0 = xf + d0; if (sg) z0 = sigm(z0);
            float z1 = xf + d1; if (sg) z1 = sigm(z1);
            float z2 = xf + d2; if (sg) z2 = sigm(z2);
            size_t rb = ((size_t)row * FD + col) * 3;
            res[rb] = z0; res[rb + 1] = z1; res[rb + 2] = z2;
        }
}

extern "C" void kernel_launch(void* const* d_in, const int* in_sizes, int n_in,
                              void* d_out, int out_size, void* d_ws, size_t ws_size,
                              hipStream_t stream) {
    const float* x    = (const float*)d_in[0];
    const float* gnnw = (const float*)d_in[1];
    const float* gnnb = (const float*)d_in[2];
    const float* wih  = (const float*)d_in[3];
    const float* whh  = (const float*)d_in[4];
    const float* bih  = (const float*)d_in[5];
    const float* bhh  = (const float*)d_in[6];
    const float* fcw  = (const float*)d_in[7];
    const float* fcb  = (const float*)d_in[8];
    const int*   adj  = (const int*)d_in[9];

    float* out = (float*)d_out;
    float* out_pred = out;
    float* out_res  = out + (size_t)NN_ * FD;
    float* out_adj  = out + (size_t)NN_ * FD * 4;

    // ws layout (~60 MB):
    char* ws = (char*)d_ws;
    float*          dinv  = (float*)ws;                          // 49,152
    unsigned short* R1    = (unsigned short*)(ws + 49152);       // 6,291,456 (yT -> h)
    unsigned short* R2    = (unsigned short*)(ws + 6340608);     // 6,291,456 (xt)
    unsigned short* wb    = (unsigned short*)(ws + 12632064);    // 3,538,944
    unsigned short* pbuf  = (unsigned short*)(ws + 16171008);    // 25,165,824
    unsigned short* gX2   = pbuf;                                // later lifetime
    unsigned char*  abits = (unsigned char*)(ws + 41336832);     // 6,291,456 (bit planes)
    float*          cbuf  = (float*)(ws + 47628288);             // 12,582,912
    const unsigned short* wihb = wb;
    const unsigned short* whhb = wb + 786432;
    const unsigned short* fcwb = wb + 1572864;
    (void)ws_size; (void)in_sizes; (void)n_in; (void)out_size;

    adj_pass<<<dim3(4096), 256, 0, stream>>>(adj, out_adj, abits, dinv, wih, whh, fcw, wb);
    gemm_xw<<<dim3(64, 4, 3), 256, 0, stream>>>(x, gnnw, dinv, R1 /*yT*/);
    gemm_agg<<<dim3(768), 256, 0, stream>>>(abits, R1 /*yT*/, pbuf);
    agg_reduce<<<dim3(1536), 256, 0, stream>>>(pbuf, dinv, gnnb, R2 /*xt*/);
    // gateX (+fused t=0 cell): A=xt, W=wih -> gX2, cbuf, h
    lstm_mm<<<dim3(768), 256, 0, stream>>>(R2 /*xt*/, wihb, bih, bhh, gX2, cbuf, R1 /*h*/, 0);
    for (int tstep = 1; tstep < 5; ++tstep)
        lstm_mm<<<dim3(768), 256, 0, stream>>>(R1 /*h*/, whhb, nullptr, nullptr, gX2, cbuf, R1 /*h*/, 1);
    fc_final<<<dim3(4, 64), 256, 0, stream>>>(R1 /*h_last*/, fcwb, fcb, x, out_pred, out_res);
}